// Round 12
// baseline (72.670 us; speedup 1.0000x reference)
//
#include <hip/hip_runtime.h>
#include <stdint.h>

typedef __bf16 bf16_t;
typedef __bf16 bf16x8 __attribute__((ext_vector_type(8)));
typedef float  f32x4  __attribute__((ext_vector_type(4)));
typedef float  f32x16 __attribute__((ext_vector_type(16)));

// LDS layout (bytes): B0 [0,18432) B1 [18432,36864) A0 [36864,40960) A1 [40960,45056)
// epilogue reduce unions from 0 (needs 49152)
#define LDS_TOTAL 49152

// async global->LDS, 16B/lane; LDS dest = wave-uniform base + lane*16
__device__ __forceinline__ void gld_lds16(const void* g, void* l) {
  __builtin_amdgcn_global_load_lds(
      (const __attribute__((address_space(1))) uint32_t*)g,
      (__attribute__((address_space(3))) uint32_t*)(uintptr_t)l,
      16, 0, 0);
}

// ---------------- weight repack into step-major layout (verified R6-R11) ----------------
// Wf2[s][o][kk], s=0..323, o=0..63, kk=kh*8+j (16 bf16 per (s,o))
// spline steps s = q*9 + tap (q=0..31 channel-pair): c = q*2+kh, f = c*9+tap
// silu steps   s = 288 + cq*9 + tap (cq=0..3): c = cq*16+kk, f = c*9+tap
__global__ __launch_bounds__(256) void prep_w_kernel(
    const float* __restrict__ bw, const float* __restrict__ sw,
    const float* __restrict__ ss, bf16_t* __restrict__ Wf2) {
  int idx = blockIdx.x * 256 + threadIdx.x;   // < 324*64*16 = 331776
  int kk = idx & 15, o = (idx >> 4) & 63, s = idx >> 10;
  int kh = kk >> 3, j = kk & 7;
  float v;
  if (s < 288) {
    int q = s / 9, tap = s - q * 9;
    int c = q * 2 + kh;
    int f = c * 9 + tap;
    v = sw[(o * 576 + f) * 8 + j] * ss[o * 576 + f];
  } else {
    int t2 = s - 288;
    int cq = t2 / 9, tap = t2 - cq * 9;
    int c = cq * 16 + kk;
    int f = c * 9 + tap;
    v = bw[o * 576 + f];
  }
  Wf2[idx] = (bf16_t)v;
}

// ---------------- main fused kernel: producer/consumer wave specialization ----------------
// block = 64 px (8x8) x 64 och; 8 waves:
//   waves 0..3: consumers, K split by taps {0,1}{2,3}{4,5}{6,7,8} -> pure ds_read+MFMA
//   waves 4..7: producers -> XLOAD (2 ahead) + window/silu VALU + A ds_write + B DMA
// One barrier per chunk; producer vmcnt drain hides behind consumer compute.
__global__ __launch_bounds__(512, 4) void convkan_kernel(
    const float* __restrict__ X, const bf16_t* __restrict__ Wf2,
    float* __restrict__ out) {
  extern __shared__ char smraw[];
  char* const Bb0 = smraw;
  char* const Bb1 = smraw + 18432;
  char* const Ab0 = smraw + 36864;
  char* const Ab1 = smraw + 40960;

  const int t    = threadIdx.x;
  const int lane = t & 63;
  const int w    = t >> 6;          // 0..7
  const bool prod = (w >= 4);
  const int pt   = t & 255;         // producer-local thread (== t-256 when prod)

  const int b   = blockIdx.x;
  const int rb  = ((b & 7) << 6) | (b >> 3);   // XCD-chunked (512%8==0, bijective)
  const int img = rb >> 6;
  const int rem = rb & 63;
  const int ohb = rem >> 3, owb = rem & 7;

  // ---- producer A-staging geometry: (channel-half h, halo cell) on 10x12 grid ----
  const int h   = pt >> 7;
  const int idx = pt & 127;
  const int row = idx / 12, col = idx - row * 12;
  const bool valid = (idx < 120) && (col < 10);
  const int ih = ohb * 8 + row - 1;
  const int iw = owb * 8 + col - 1;
  const bool inb = valid && ((unsigned)ih < 64u) && ((unsigned)iw < 64u);
  const float* Ximg = X + (((size_t)img * 64) << 12);
  const int pixoff = (ih << 6) + iw;
  const int pw = pt >> 6;           // producer wave 0..3

  // ---- consumer read geometry (verified R9-R11 12-wide conventions) ----
  const int r    = lane & 31;
  const int kh   = lane >> 5;
  const int khq  = kh * 128;
  const int pb0  = (r >> 3) * 12 + (r & 7);
  const int pb1  = pb0 + 48;
  const int tap0 = (w < 3) ? (w * 2) : 6;   // only meaningful for w<4
  const int ntap = (w < 3) ? 2 : 3;

  const float G0 = -2.2f, G1 = 2.2f, INVH = 2.5f;

  f32x16 acc[2][2];
  #pragma unroll
  for (int a = 0; a < 2; ++a)
    #pragma unroll
    for (int c = 0; c < 2; ++c) acc[a][c] = (f32x16)0.0f;

  auto XLOAD = [&](int cs, float* xr) {
    if (cs < 32) {
      xr[0] = inb ? Ximg[(((size_t)(2 * cs + h)) << 12) + pixoff] : 0.0f;
    } else {
      const int c0 = (cs - 32) * 16 + h * 8;
      #pragma unroll
      for (int j = 0; j < 8; ++j)
        xr[j] = inb ? Ximg[(((size_t)(c0 + j)) << 12) + pixoff] : 0.0f;
    }
  };

  auto WINW = [&](int cs, const float* xr, char* abuf) {
    if (cs < 32) {
      // uniform cubic B-spline window (verified R1-R11)
      float x  = xr[0];
      float tt = (x - G0) * INVH;
      int  i0  = (int)tt;
      i0 = i0 < 0 ? 0 : (i0 > 10 ? 10 : i0);
      float u  = tt - (float)i0;
      float um = 1.0f - u;
      float u2 = u * u, u3 = u2 * u;
      float w0 = um * um * um * (1.0f / 6.0f);
      float w1 = (3.0f * u3 - 6.0f * u2 + 4.0f) * (1.0f / 6.0f);
      float w2 = (-3.0f * u3 + 3.0f * u2 + 3.0f * u + 1.0f) * (1.0f / 6.0f);
      float w3 = u3 * (1.0f / 6.0f);
      bool inr = (x >= G0) & (x < G1);

      union { bf16_t hh4[4]; unsigned long long u64; } pk;
      pk.hh4[0] = (bf16_t)w0; pk.hh4[1] = (bf16_t)w1;
      pk.hh4[2] = (bf16_t)w2; pk.hh4[3] = (bf16_t)w3;
      unsigned long long a = inr ? pk.u64 : 0ull;

      int sh = (i0 - 3) * 16;
      unsigned long long lo, hi;
      if (sh >= 0) {
        lo = (sh < 64) ? (a << (sh & 63)) : 0ull;
        hi = (sh == 0) ? 0ull
             : ((sh < 64) ? (a >> ((64 - sh) & 63)) : (a << ((sh - 64) & 63)));
      } else {
        lo = a >> ((-sh) & 63);
        hi = 0ull;
      }
      uint4 wv;
      wv.x = (unsigned)(lo & 0xffffffffull); wv.y = (unsigned)(lo >> 32);
      wv.z = (unsigned)(hi & 0xffffffffull); wv.w = (unsigned)(hi >> 32);
      if (valid) *(uint4*)(abuf + ((h * 128 + idx) << 4)) = wv;
    } else {
      union { bf16_t hh8[8]; bf16x8 v; } pk;
      #pragma unroll
      for (int j = 0; j < 8; ++j) {
        float x = xr[j];
        pk.hh8[j] = (bf16_t)(x / (1.0f + __expf(-x)));
      }
      if (valid) *(bf16x8*)(abuf + ((2 * idx + h) << 4)) = pk.v;
    }
  };

  auto STAGEB = [&](int cs, char* bufB) {
    const bf16_t* bsrc = Wf2 + (size_t)(cs < 32 ? cs * 9 : 288 + (cs - 32) * 9) * 1024;
    #pragma unroll
    for (int u = 0; u < 4; ++u)
      gld_lds16(bsrc + ((u * 256 + pt) << 3), bufB + ((u * 256 + (pw << 6)) << 4));
    if (pt < 128)
      gld_lds16(bsrc + ((1024 + pt) << 3), bufB + ((1024 + (pw << 6)) << 4));
  };

  auto COMPUTE = [&](int ci, const char* bufA, const char* bufB) {
    const bool spline = (ci < 32);
    #pragma unroll
    for (int tt = 0; tt < 3; ++tt) if (tt < ntap) {
      const int tap  = tap0 + tt;
      const int ki   = (tap * 11) >> 5;
      const int koff = ki * 12 + (tap - 3 * ki);
      const int c0 = pb0 + koff, c1 = pb1 + koff;
      const int au0 = spline ? (khq + c0) : (2 * c0 + kh);
      const int au1 = spline ? (khq + c1) : (2 * c1 + kh);
      bf16x8 A0f = *(const bf16x8*)(bufA + (au0 << 4));
      bf16x8 A1f = *(const bf16x8*)(bufA + (au1 << 4));
      const char* bt = bufB + (tap << 11) + r * 32 + kh * 16;
      bf16x8 B0f = *(const bf16x8*)bt;
      bf16x8 B1f = *(const bf16x8*)(bt + 1024);
      acc[0][0] = __builtin_amdgcn_mfma_f32_32x32x16_bf16(A0f, B0f, acc[0][0], 0, 0, 0);
      acc[0][1] = __builtin_amdgcn_mfma_f32_32x32x16_bf16(A0f, B1f, acc[0][1], 0, 0, 0);
      acc[1][0] = __builtin_amdgcn_mfma_f32_32x32x16_bf16(A1f, B0f, acc[1][0], 0, 0, 0);
      acc[1][1] = __builtin_amdgcn_mfma_f32_32x32x16_bf16(A1f, B1f, acc[1][1], 0, 0, 0);
    }
  };

  // ---- prologue: producers fill chunk 0 ----
  float xP[8], xQ[8];
  if (prod) {
    XLOAD(0, xP);
    WINW(0, xP, Ab0);
    XLOAD(1, xP);            // xP now holds x(1)
    STAGEB(0, Bb0);
  }
  __syncthreads();

  // ---- main loop: pair-unrolled so buffers and xP/xQ roles are static ----
  for (int i = 0; i < 18; ++i) {
    {
      const int ci = 2 * i;                 // consumers eat A0/B0
      if (prod) {
        if (ci + 2 < 36) XLOAD(ci + 2, xQ);
        if (ci + 1 < 36) { STAGEB(ci + 1, Bb1); WINW(ci + 1, xP, Ab1); }
      } else {
        COMPUTE(ci, Ab0, Bb0);
      }
      __syncthreads();
    }
    {
      const int ci = 2 * i + 1;             // consumers eat A1/B1
      if (prod) {
        if (ci + 2 < 36) XLOAD(ci + 2, xP);
        if (ci + 1 < 36) { STAGEB(ci + 1, Bb0); WINW(ci + 1, xQ, Ab0); }
      } else {
        COMPUTE(ci, Ab1, Bb1);
      }
      __syncthreads();
    }
  }

  // ---- 4-way K-reduce: consumer waves 1-3 dump, wave 0 combines + stores ----
  float* red = (float*)smraw;
  if (w >= 1 && w <= 3) {
    #pragma unroll
    for (int pxt = 0; pxt < 2; ++pxt)
      #pragma unroll
      for (int ot = 0; ot < 2; ++ot)
        #pragma unroll
        for (int q = 0; q < 16; ++q)
          red[(((w - 1) * 64) + (pxt * 2 + ot) * 16 + q) * 64 + lane] = acc[pxt][ot][q];
  }
  __syncthreads();
  if (w == 0) {
    #pragma unroll
    for (int pxt = 0; pxt < 2; ++pxt) {
      #pragma unroll
      for (int ot = 0; ot < 2; ++ot) {
        const int o = ot * 32 + r;
        float* obase = out + (((size_t)(img * 64 + o)) << 12);
        #pragma unroll
        for (int g = 0; g < 4; ++g) {
          f32x4 v;
          #pragma unroll
          for (int iq = 0; iq < 4; ++iq) {
            int q = g * 4 + iq;
            int ri = (pxt * 2 + ot) * 16 + q;
            v[iq] = acc[pxt][ot][q]
                  + red[(0 * 64 + ri) * 64 + lane]
                  + red[(1 * 64 + ri) * 64 + lane]
                  + red[(2 * 64 + ri) * 64 + lane];
          }
          int px = pxt * 32 + 8 * g + 4 * kh;
          *(f32x4*)(obase + (ohb * 8 + (px >> 3)) * 64 + owb * 8 + (px & 7)) = v;
        }
      }
    }
  }
}

extern "C" void kernel_launch(void* const* d_in, const int* in_sizes, int n_in,
                              void* d_out, int out_size, void* d_ws, size_t ws_size,
                              hipStream_t stream) {
  const float* x  = (const float*)d_in[0];
  const float* bw = (const float*)d_in[1];
  const float* sw = (const float*)d_in[2];
  const float* ss = (const float*)d_in[3];

  bf16_t* Wf2 = (bf16_t*)d_ws;        // 324*64*16*2 = 663,552 B
  float*  o   = (float*)d_out;

  prep_w_kernel<<<1296, 256, 0, stream>>>(bw, sw, ss, Wf2);
  convkan_kernel<<<512, 512, LDS_TOTAL, stream>>>(x, Wf2, o);
}

// Round 13
// 48.928 us; speedup vs baseline: 1.4853x; 1.4853x over previous
//
#include <hip/hip_runtime.h>
#include <stdint.h>

typedef __bf16 bf16_t;
typedef __bf16 bf16x8 __attribute__((ext_vector_type(8)));
typedef float  f32x4  __attribute__((ext_vector_type(4)));
typedef float  f32x16 __attribute__((ext_vector_type(16)));

// LDS layout (bytes): Bb0 [0,20480) Bb1 [20480,40960) Ab0 [40960,45056) Ab1 [45056,49152)
// (B buffers: 18432 data + 2048 pad for the uniform 5th DMA)
// epilogue reduce unions from 0 (needs 49152)
#define LDS_TOTAL 49152

// async global->LDS, 16B/lane; LDS dest = wave-uniform base + lane*16 (global src per-lane)
__device__ __forceinline__ void gld_lds16(const void* g, void* l) {
  __builtin_amdgcn_global_load_lds(
      (const __attribute__((address_space(1))) uint32_t*)g,
      (__attribute__((address_space(3))) uint32_t*)(uintptr_t)l,
      16, 0, 0);
}

// ---------------- weight repack, step-major + kh-major inner layout ----------------
// Wf2[s][kh][o][j]  (s=0..323, kh=0..1, o=0..63, j=0..7); element = s*1024 + kh*512 + o*8 + j
// value for (s,o,kk=kh*8+j):
//   spline s<288: q=s/9, tap=s%9, c=q*2+kh, f=c*9+tap, v = sw[(o*576+f)*8+j]*ss[o*576+f]
//   silu  s>=288: cq=(s-288)/9, tap=(s-288)%9, c=cq*16+kk, f=c*9+tap, v = bw[o*576+f]
__global__ __launch_bounds__(256) void prep_w_kernel(
    const float* __restrict__ bw, const float* __restrict__ sw,
    const float* __restrict__ ss, bf16_t* __restrict__ Wf2) {
  int idx = blockIdx.x * 256 + threadIdx.x;   // < 324*1024 = 331776
  int j = idx & 7, o = (idx >> 3) & 63, kh = (idx >> 9) & 1, s = idx >> 10;
  int kk = kh * 8 + j;
  float v;
  if (s < 288) {
    int q = s / 9, tap = s - q * 9;
    int c = q * 2 + kh;
    int f = c * 9 + tap;
    v = sw[(o * 576 + f) * 8 + j] * ss[o * 576 + f];
  } else {
    int t2 = s - 288;
    int cq = t2 / 9, tap = t2 - cq * 9;
    int c = cq * 16 + kk;
    int f = c * 9 + tap;
    v = bw[o * 576 + f];
  }
  Wf2[idx] = (bf16_t)v;
}

// ---------------- main fused kernel: R11 structure + counted-vmcnt raw barriers ----------------
// block = 64 px (8x8) x 64 och; 4 waves, each produces AND consumes;
// K split by taps {0,1}{2,3}{4,5}{6,7,8}. A double-buffer built by VALU (x loaded
// 2 chunks ahead, loads survive barriers); B double-buffer via 5-uniform DMA.
__global__ __launch_bounds__(256, 2) void convkan_kernel(
    const float* __restrict__ X, const bf16_t* __restrict__ Wf2,
    float* __restrict__ out) {
  extern __shared__ char smraw[];
  char* const Bb0 = smraw;
  char* const Bb1 = smraw + 20480;
  char* const Ab0 = smraw + 40960;
  char* const Ab1 = smraw + 45056;

  const int t    = threadIdx.x;
  const int lane = t & 63;
  const int w    = t >> 6;        // wave 0..3 (tap group)

  const int b   = blockIdx.x;
  const int rb  = ((b & 7) << 6) | (b >> 3);   // XCD-chunked (512%8==0, bijective)
  const int img = rb >> 6;
  const int rem = rb & 63;
  const int ohb = rem >> 3, owb = rem & 7;

  // ---- A staging geometry: thread -> (channel-half h, halo cell) on 10x12 grid ----
  const int h   = t >> 7;
  const int idx = t & 127;
  const int row = idx / 12, col = idx - row * 12;
  const bool valid = (idx < 120) && (col < 10);
  const int ih = ohb * 8 + row - 1;
  const int iw = owb * 8 + col - 1;
  const bool inb = valid && ((unsigned)ih < 64u) && ((unsigned)iw < 64u);
  const float* Ximg = X + (((size_t)img * 64) << 12);
  const int   psafe = inb ? ((ih << 6) + iw) : 0;   // clamped: loads always issue
  const float xmask = inb ? 1.0f : 0.0f;

  // ---- compute-read geometry (verified R9-R11 12-wide conventions) ----
  const int r    = lane & 31;
  const int kh   = lane >> 5;
  const int khq  = kh * 128;
  const int pb0  = (r >> 3) * 12 + (r & 7);
  const int pb1  = pb0 + 48;
  const int tap0 = (w < 3) ? (w * 2) : 6;
  const int ntap = (w < 3) ? 2 : 3;

  const float G0 = -2.2f, G1 = 2.2f, INVH = 2.5f;

  f32x16 acc[2][2];
  #pragma unroll
  for (int a = 0; a < 2; ++a)
    #pragma unroll
    for (int c = 0; c < 2; ++c) acc[a][c] = (f32x16)0.0f;

  float xP[8], xQ[8];

  auto XLOAD = [&](int cs, float* xr) {
    if (cs < 32) {
      xr[0] = Ximg[(((size_t)(2 * cs + h)) << 12) + psafe] * xmask;   // 1 load
    } else {
      const int c0 = (cs - 32) * 16 + h * 8;
      #pragma unroll
      for (int j = 0; j < 8; ++j)                                      // 8 loads
        xr[j] = Ximg[(((size_t)(c0 + j)) << 12) + psafe] * xmask;
    }
  };

  auto WINW = [&](int cs, const float* xr, char* abuf) {
    if (cs < 32) {
      // uniform cubic B-spline window (verified R1-R12)
      float x  = xr[0];
      float tt = (x - G0) * INVH;
      int  i0  = (int)tt;
      i0 = i0 < 0 ? 0 : (i0 > 10 ? 10 : i0);
      float u  = tt - (float)i0;
      float um = 1.0f - u;
      float u2 = u * u, u3 = u2 * u;
      float w0 = um * um * um * (1.0f / 6.0f);
      float w1 = (3.0f * u3 - 6.0f * u2 + 4.0f) * (1.0f / 6.0f);
      float w2 = (-3.0f * u3 + 3.0f * u2 + 3.0f * u + 1.0f) * (1.0f / 6.0f);
      float w3 = u3 * (1.0f / 6.0f);
      bool inr = (x >= G0) & (x < G1);

      union { bf16_t hh4[4]; unsigned long long u64; } pk;
      pk.hh4[0] = (bf16_t)w0; pk.hh4[1] = (bf16_t)w1;
      pk.hh4[2] = (bf16_t)w2; pk.hh4[3] = (bf16_t)w3;
      unsigned long long a = inr ? pk.u64 : 0ull;

      int sh = (i0 - 3) * 16;
      unsigned long long lo, hi;
      if (sh >= 0) {
        lo = (sh < 64) ? (a << (sh & 63)) : 0ull;
        hi = (sh == 0) ? 0ull
             : ((sh < 64) ? (a >> ((64 - sh) & 63)) : (a << ((sh - 64) & 63)));
      } else {
        lo = a >> ((-sh) & 63);
        hi = 0ull;
      }
      uint4 wv;
      wv.x = (unsigned)(lo & 0xffffffffull); wv.y = (unsigned)(lo >> 32);
      wv.z = (unsigned)(hi & 0xffffffffull); wv.w = (unsigned)(hi >> 32);
      if (valid) *(uint4*)(abuf + ((h * 128 + idx) << 4)) = wv;
    } else {
      union { bf16_t hh8[8]; bf16x8 v; } pk;
      #pragma unroll
      for (int j = 0; j < 8; ++j) {
        float x = xr[j];
        pk.hh8[j] = (bf16_t)(x / (1.0f + __expf(-x)));
      }
      if (valid) *(bf16x8*)(abuf + ((2 * idx + h) << 4)) = pk.v;
    }
  };

  // every wave issues EXACTLY 5 DMA (vmcnt-uniform); waves 2,3's 5th lands in pad
  auto STAGEB = [&](int cs, char* bufB) {
    const bf16_t* bsrc = Wf2 + (size_t)(cs < 32 ? cs * 9 : 288 + (cs - 32) * 9) * 1024;
    #pragma unroll
    for (int u = 0; u < 4; ++u)
      gld_lds16(bsrc + ((u * 256 + t) << 3), bufB + ((u * 256 + (w << 6)) << 4));
    gld_lds16(bsrc + ((t < 128 ? 1024 + t : t) << 3), bufB + ((1024 + (w << 6)) << 4));
  };

  auto COMPUTE = [&](int ci, const char* bufA, const char* bufB) {
    const bool spline = (ci < 32);
    #pragma unroll
    for (int tt = 0; tt < 3; ++tt) if (tt < ntap) {
      const int tap  = tap0 + tt;
      const int ki   = (tap * 11) >> 5;
      const int koff = ki * 12 + (tap - 3 * ki);
      const int c0 = pb0 + koff, c1 = pb1 + koff;
      const int au0 = spline ? (khq + c0) : (2 * c0 + kh);
      const int au1 = spline ? (khq + c1) : (2 * c1 + kh);
      bf16x8 A0f = *(const bf16x8*)(bufA + (au0 << 4));
      bf16x8 A1f = *(const bf16x8*)(bufA + (au1 << 4));
      const char* bt = bufB + (tap << 11) + (kh << 10) + (r << 4);
      bf16x8 B0f = *(const bf16x8*)bt;
      bf16x8 B1f = *(const bf16x8*)(bt + 512);
      acc[0][0] = __builtin_amdgcn_mfma_f32_32x32x16_bf16(A0f, B0f, acc[0][0], 0, 0, 0);
      acc[0][1] = __builtin_amdgcn_mfma_f32_32x32x16_bf16(A0f, B1f, acc[0][1], 0, 0, 0);
      acc[1][0] = __builtin_amdgcn_mfma_f32_32x32x16_bf16(A1f, B0f, acc[1][0], 0, 0, 0);
      acc[1][1] = __builtin_amdgcn_mfma_f32_32x32x16_bf16(A1f, B1f, acc[1][1], 0, 0, 0);
    }
  };

// per-chunk body: issue 5 DMA, then k X-loads (pinned order), compute, then
// counted wait (drains DMA+ds_write; X-loads stay in flight) + raw barrier.
#define BODY(CI, AU, BU, AF, BF, XU, XF, VM, DO_X)                        \
  do {                                                                     \
    STAGEB((CI) + 1, BF);                                                  \
    __builtin_amdgcn_sched_barrier(0);                                     \
    if (DO_X) XLOAD((CI) + 2, XF);                                         \
    __builtin_amdgcn_sched_barrier(0);                                     \
    WINW((CI) + 1, XU, AF);                                                \
    COMPUTE((CI), AU, BU);                                                 \
    asm volatile("s_waitcnt vmcnt(" #VM ") lgkmcnt(0)" ::: "memory");      \
    __builtin_amdgcn_sched_barrier(0);                                     \
    __builtin_amdgcn_s_barrier();                                          \
  } while (0)

  // ---- prologue: fill chunk 0, preload x(1); DMA drained, x(1) stays in flight ----
  XLOAD(0, xP);
  WINW(0, xP, Ab0);                 // compiler waits x(0) here
  STAGEB(0, Bb0);
  __builtin_amdgcn_sched_barrier(0);
  XLOAD(1, xP);
  __builtin_amdgcn_sched_barrier(0);
  asm volatile("s_waitcnt vmcnt(1) lgkmcnt(0)" ::: "memory");
  __builtin_amdgcn_s_barrier();

  // ---- main: chunks 0..29 (spline prefetch, k=1) ----
  for (int i = 0; i < 15; ++i) {
    BODY(2 * i,     Ab0, Bb0, Ab1, Bb1, xP, xQ, 1, true);
    BODY(2 * i + 1, Ab1, Bb1, Ab0, Bb0, xQ, xP, 1, true);
  }
  // chunks 30..33 (silu prefetch, k=8)
  BODY(30, Ab0, Bb0, Ab1, Bb1, xP, xQ, 8, true);
  BODY(31, Ab1, Bb1, Ab0, Bb0, xQ, xP, 8, true);
  BODY(32, Ab0, Bb0, Ab1, Bb1, xP, xQ, 8, true);
  BODY(33, Ab1, Bb1, Ab0, Bb0, xQ, xP, 8, true);
  // chunk 34: stage 35, no prefetch
  BODY(34, Ab0, Bb0, Ab1, Bb1, xP, xQ, 0, false);
  // chunk 35: compute only
  COMPUTE(35, Ab1, Bb1);
#undef BODY

  // ---- 4-way K-reduce: waves 1-3 dump, wave 0 combines + stores (R8/R11 verbatim) ----
  __syncthreads();
  float* red = (float*)smraw;
  if (w != 0) {
    #pragma unroll
    for (int pxt = 0; pxt < 2; ++pxt)
      #pragma unroll
      for (int ot = 0; ot < 2; ++ot)
        #pragma unroll
        for (int q = 0; q < 16; ++q)
          red[(((w - 1) * 64) + (pxt * 2 + ot) * 16 + q) * 64 + lane] = acc[pxt][ot][q];
  }
  __syncthreads();
  if (w == 0) {
    #pragma unroll
    for (int pxt = 0; pxt < 2; ++pxt) {
      #pragma unroll
      for (int ot = 0; ot < 2; ++ot) {
        const int o = ot * 32 + r;
        float* obase = out + (((size_t)(img * 64 + o)) << 12);
        #pragma unroll
        for (int g = 0; g < 4; ++g) {
          f32x4 v;
          #pragma unroll
          for (int iq = 0; iq < 4; ++iq) {
            int q = g * 4 + iq;
            int ri = (pxt * 2 + ot) * 16 + q;
            v[iq] = acc[pxt][ot][q]
                  + red[(0 * 64 + ri) * 64 + lane]
                  + red[(1 * 64 + ri) * 64 + lane]
                  + red[(2 * 64 + ri) * 64 + lane];
          }
          int px = pxt * 32 + 8 * g + 4 * kh;
          *(f32x4*)(obase + (ohb * 8 + (px >> 3)) * 64 + owb * 8 + (px & 7)) = v;
        }
      }
    }
  }
}

extern "C" void kernel_launch(void* const* d_in, const int* in_sizes, int n_in,
                              void* d_out, int out_size, void* d_ws, size_t ws_size,
                              hipStream_t stream) {
  const float* x  = (const float*)d_in[0];
  const float* bw = (const float*)d_in[1];
  const float* sw = (const float*)d_in[2];
  const float* ss = (const float*)d_in[3];

  bf16_t* Wf2 = (bf16_t*)d_ws;        // 324*1024*2 = 663,552 B
  float*  o   = (float*)d_out;

  prep_w_kernel<<<1296, 256, 0, stream>>>(bw, sw, ss, Wf2);
  convkan_kernel<<<512, 256, LDS_TOTAL, stream>>>(x, Wf2, o);
}